// Round 1
// baseline (442.103 us; speedup 1.0000x reference)
//
#include <hip/hip_runtime.h>
#include <math.h>

#define BB 32
#define SS 1024
#define DH 512      // DEC_HID
#define EH2 1024    // 2*ENC_HID
#define WROW 1536   // in_dim = 2*ENC_HID + DEC_HID
#define NEGV -1.0e10f

#define TM 128
#define TN 128
#define TK 32
#define LPAD 132    // padded inner stride for [TK][TM] transposed tiles

// ---------------- Kernel A: h_proj[b,d] = sum_k hidden[b,k]*W[d,k] + bias[d]
__global__ void hproj_kernel(const float* __restrict__ hidden,
                             const float* __restrict__ W,
                             const float* __restrict__ bias,
                             float* __restrict__ hproj) {
    int wave = (int)((blockIdx.x * blockDim.x + threadIdx.x) >> 6);
    int lane = threadIdx.x & 63;
    if (wave >= BB * DH) return;
    int b = wave >> 9;       // /512
    int d = wave & 511;
    const float* hrow = hidden + b * DH;
    const float* wrow = W + (size_t)d * WROW;   // Wh = W[:, :512]
    float sum = 0.f;
#pragma unroll
    for (int u = 0; u < 8; ++u) {
        int k = lane + 64 * u;
        sum = fmaf(hrow[k], wrow[k], sum);
    }
#pragma unroll
    for (int off = 32; off > 0; off >>= 1)
        sum += __shfl_xor(sum, off, 64);
    if (lane == 0) hproj[wave] = sum + bias[d];
}

// ---------------- Kernel B: fused e_proj GEMM + tanh + v-dot partial scores
// grid: 32 (b) x 8 (s-chunk of 128) x 4 (d-chunk of 128) = 1024 blocks, 256 thr
__global__ void energy_kernel(const float* __restrict__ enc,
                              const float* __restrict__ W,
                              const float* __restrict__ hproj,
                              const float* __restrict__ v,
                              float* __restrict__ scores) {
    __shared__ float a_s[TK][LPAD];  // [kk][s-row]
    __shared__ float b_s[TK][LPAD];  // [kk][d-col]

    int tid = threadIdx.x;
    int bid = blockIdx.x;
    int dChunk = bid & 3;
    int sChunk = (bid >> 2) & 7;
    int b = bid >> 5;
    int s0 = sChunk * TM;
    int d0 = dChunk * TN;
    int tx = tid & 15;    // col group (8 cols each)
    int ty = tid >> 4;    // row group (8 rows each)

    const float* encBase = enc + ((size_t)b * SS + s0) * EH2;
    const float* wBase = W + (size_t)d0 * WROW + DH;   // We = W[:, 512:]

    float acc[8][8];
#pragma unroll
    for (int i = 0; i < 8; ++i)
#pragma unroll
        for (int j = 0; j < 8; ++j) acc[i][j] = 0.f;

    for (int kt = 0; kt < EH2; kt += TK) {
        // stage A: 128 s-rows x 32 k, transposed into LDS
#pragma unroll
        for (int q = 0; q < 4; ++q) {
            int f = tid + 256 * q;          // float4 index 0..1023
            int row = f >> 3;               // 8 float4 per row of 32 k
            int kin = (f & 7) * 4;
            float4 val = *(const float4*)(encBase + (size_t)row * EH2 + kt + kin);
            a_s[kin + 0][row] = val.x;
            a_s[kin + 1][row] = val.y;
            a_s[kin + 2][row] = val.z;
            a_s[kin + 3][row] = val.w;
        }
        // stage B: 128 d-cols x 32 k, transposed into LDS
#pragma unroll
        for (int q = 0; q < 4; ++q) {
            int f = tid + 256 * q;
            int col = f >> 3;
            int kin = (f & 7) * 4;
            float4 val = *(const float4*)(wBase + (size_t)col * WROW + kt + kin);
            b_s[kin + 0][col] = val.x;
            b_s[kin + 1][col] = val.y;
            b_s[kin + 2][col] = val.z;
            b_s[kin + 3][col] = val.w;
        }
        __syncthreads();

#pragma unroll 4
        for (int kk = 0; kk < TK; ++kk) {
            float av[8], bv[8];
            *(float4*)&av[0] = *(const float4*)&a_s[kk][ty * 8];
            *(float4*)&av[4] = *(const float4*)&a_s[kk][ty * 8 + 4];
            *(float4*)&bv[0] = *(const float4*)&b_s[kk][tx * 8];
            *(float4*)&bv[4] = *(const float4*)&b_s[kk][tx * 8 + 4];
#pragma unroll
            for (int i = 0; i < 8; ++i)
#pragma unroll
                for (int j = 0; j < 8; ++j)
                    acc[i][j] = fmaf(av[i], bv[j], acc[i][j]);
        }
        __syncthreads();
    }

    // epilogue: scores partial = sum_d tanh(e_proj + h_proj) * v
    float hp[8], vv[8];
#pragma unroll
    for (int j = 0; j < 8; ++j) {
        hp[j] = hproj[b * DH + d0 + tx * 8 + j];
        vv[j] = v[d0 + tx * 8 + j];
    }
#pragma unroll
    for (int i = 0; i < 8; ++i) {
        float p = 0.f;
#pragma unroll
        for (int j = 0; j < 8; ++j)
            p += tanhf(acc[i][j] + hp[j]) * vv[j];
        // reduce across the 16 tx lanes (same ty within the wave)
        p += __shfl_xor(p, 1, 64);
        p += __shfl_xor(p, 2, 64);
        p += __shfl_xor(p, 4, 64);
        p += __shfl_xor(p, 8, 64);
        if (tx == 0)
            atomicAdd(&scores[b * SS + s0 + ty * 8 + i], p);
    }
}

// ---------------- Kernel C: masked softmax over S per batch row
__global__ void softmax_kernel(const float* __restrict__ scores,
                               const int* __restrict__ mask,
                               float* __restrict__ out) {
    __shared__ float red[8];
    int b = blockIdx.x;
    int tid = threadIdx.x;       // 256
    int lane = tid & 63;
    int wid = tid >> 6;          // 0..3

    float x[4];
    float mx = -INFINITY;
#pragma unroll
    for (int u = 0; u < 4; ++u) {
        int s = tid + 256 * u;
        float sc = scores[b * SS + s];
        if (mask[b * SS + s] == 0) sc = NEGV;
        x[u] = sc;
        mx = fmaxf(mx, sc);
    }
#pragma unroll
    for (int off = 32; off > 0; off >>= 1)
        mx = fmaxf(mx, __shfl_xor(mx, off, 64));
    if (lane == 0) red[wid] = mx;
    __syncthreads();
    mx = fmaxf(fmaxf(red[0], red[1]), fmaxf(red[2], red[3]));

    float sum = 0.f;
#pragma unroll
    for (int u = 0; u < 4; ++u) {
        x[u] = expf(x[u] - mx);
        sum += x[u];
    }
#pragma unroll
    for (int off = 32; off > 0; off >>= 1)
        sum += __shfl_xor(sum, off, 64);
    __syncthreads();
    if (lane == 0) red[4 + wid] = sum;
    __syncthreads();
    sum = red[4] + red[5] + red[6] + red[7];
    float inv = 1.0f / sum;
#pragma unroll
    for (int u = 0; u < 4; ++u)
        out[b * SS + tid + 256 * u] = x[u] * inv;
}

extern "C" void kernel_launch(void* const* d_in, const int* in_sizes, int n_in,
                              void* d_out, int out_size, void* d_ws, size_t ws_size,
                              hipStream_t stream) {
    const float* hidden = (const float*)d_in[0];
    const float* enc    = (const float*)d_in[1];
    const int*   mask   = (const int*)d_in[2];
    const float* W      = (const float*)d_in[3];
    const float* bias   = (const float*)d_in[4];
    const float* v      = (const float*)d_in[5];
    float* out = (float*)d_out;

    float* hproj  = (float*)d_ws;                         // 32*512 f32 = 64KB
    float* scores = (float*)((char*)d_ws + 64 * 1024);    // 32*1024 f32 = 128KB

    hipMemsetAsync(scores, 0, BB * SS * sizeof(float), stream);

    hproj_kernel<<<BB * DH / 4, 256, 0, stream>>>(hidden, W, bias, hproj);
    energy_kernel<<<BB * 8 * 4, 256, 0, stream>>>(enc, W, hproj, v, scores);
    softmax_kernel<<<BB, 256, 0, stream>>>(scores, mask, out);
}

// Round 2
// 150.100 us; speedup vs baseline: 2.9454x; 2.9454x over previous
//
#include <hip/hip_runtime.h>
#include <hip/hip_bf16.h>
#include <math.h>

#define BB 32
#define SS 1024
#define DH 512      // DEC_HID
#define EH2 1024    // 2*ENC_HID
#define WROW 1536   // in_dim
#define NEGV -1.0e10f

#define BM 128
#define BN 128
#define BK 32
#define LSTR 40     // padded LDS row stride (bf16 elems) = 80 B

typedef __attribute__((ext_vector_type(8))) short s16x8;
typedef __attribute__((ext_vector_type(4))) float f32x4;

// ---------------- Kernel A: h_proj[b,d] = hidden[b,:] . W[d,:512] + bias[d]
__global__ void hproj_kernel(const float* __restrict__ hidden,
                             const float* __restrict__ W,
                             const float* __restrict__ bias,
                             float* __restrict__ hproj) {
    int wave = (int)((blockIdx.x * blockDim.x + threadIdx.x) >> 6);
    int lane = threadIdx.x & 63;
    if (wave >= BB * DH) return;
    int b = wave >> 9;
    int d = wave & 511;
    const float* hrow = hidden + b * DH;
    const float* wrow = W + (size_t)d * WROW;
    float sum = 0.f;
#pragma unroll
    for (int u = 0; u < 8; ++u) {
        int k = lane + 64 * u;
        sum = fmaf(hrow[k], wrow[k], sum);
    }
#pragma unroll
    for (int off = 32; off > 0; off >>= 1)
        sum += __shfl_xor(sum, off, 64);
    if (lane == 0) hproj[wave] = sum + bias[d];
}

// ---------------- Kernel B: bf16-split MFMA GEMM + tanh·v epilogue
// grid: 256 m-blocks (b,s) x 4 n-blocks (d) = 1024 blocks, 256 threads
__global__ __launch_bounds__(256, 2)
void energy_mfma_kernel(const float* __restrict__ enc,
                        const float* __restrict__ W,
                        const float* __restrict__ hproj,
                        const float* __restrict__ v,
                        float* __restrict__ scores) {
    __shared__ unsigned short sA[2][BM * LSTR];  // [0]=hi [1]=lo
    __shared__ unsigned short sB[2][BN * LSTR];

    const int tid = threadIdx.x;
    const int lane = tid & 63;
    const int wid = tid >> 6;
    const int lr = lane & 15;
    const int lg = lane >> 4;

    const int nblk = blockIdx.x & 3;
    const int mblk = blockIdx.x >> 2;
    const int b = mblk >> 3;
    const int s0 = (mblk & 7) * BM;
    const int d0 = nblk * BN;

    const int ws = (wid >> 1) * 64;  // wave row (s) offset in tile
    const int wd = (wid & 1) * 64;   // wave col (d) offset in tile

    const float* aBase = enc + (size_t)(b * SS + s0) * EH2;
    const float* bBase = W + (size_t)d0 * WROW + DH;

    const int trow = tid >> 3;        // 0..31, +32q -> 0..127
    const int tk = (tid & 7) * 4;     // 0,4,...,28

    f32x4 acc[4][4];
#pragma unroll
    for (int m = 0; m < 4; ++m)
#pragma unroll
        for (int n = 0; n < 4; ++n) acc[m][n] = (f32x4){0.f, 0.f, 0.f, 0.f};

    float4 rA0[4], rB0[4], rA1[4], rB1[4];

    auto loadG = [&](int kt, float4* a4, float4* b4) {
#pragma unroll
        for (int q = 0; q < 4; ++q) {
            a4[q] = *(const float4*)(aBase + (size_t)(trow + 32 * q) * EH2 + kt + tk);
            b4[q] = *(const float4*)(bBase + (size_t)(trow + 32 * q) * WROW + kt + tk);
        }
    };

    auto splitWrite = [&](unsigned short* hiDst, unsigned short* loDst, const float4& val) {
        float xs[4] = {val.x, val.y, val.z, val.w};
        unsigned long long whi = 0, wlo = 0;
#pragma unroll
        for (int j = 0; j < 4; ++j) {
            unsigned int u = __builtin_bit_cast(unsigned int, xs[j]);
            unsigned int hb = u & 0xFFFF0000u;
            float rem = xs[j] - __builtin_bit_cast(float, hb);
            __hip_bfloat16 lo16 = __float2bfloat16(rem);
            unsigned long long h = (unsigned long long)(u >> 16);
            unsigned long long l = (unsigned long long)__builtin_bit_cast(unsigned short, lo16);
            whi |= h << (16 * j);
            wlo |= l << (16 * j);
        }
        *(unsigned long long*)hiDst = whi;
        *(unsigned long long*)loDst = wlo;
    };

    auto writeL = [&](const float4* a4, const float4* b4) {
#pragma unroll
        for (int q = 0; q < 4; ++q) {
            int base = (trow + 32 * q) * LSTR + tk;
            splitWrite(&sA[0][base], &sA[1][base], a4[q]);
            splitWrite(&sB[0][base], &sB[1][base], b4[q]);
        }
    };

    auto compute = [&]() {
        s16x8 aH[4], aL[4], bH[4], bL[4];
#pragma unroll
        for (int m = 0; m < 4; ++m) {
            int off = (ws + m * 16 + lr) * LSTR + lg * 8;
            aH[m] = *(const s16x8*)&sA[0][off];
            aL[m] = *(const s16x8*)&sA[1][off];
        }
#pragma unroll
        for (int n = 0; n < 4; ++n) {
            int off = (wd + n * 16 + lr) * LSTR + lg * 8;
            bH[n] = *(const s16x8*)&sB[0][off];
            bL[n] = *(const s16x8*)&sB[1][off];
        }
#pragma unroll
        for (int m = 0; m < 4; ++m)
#pragma unroll
            for (int n = 0; n < 4; ++n) {
                acc[m][n] = __builtin_amdgcn_mfma_f32_16x16x32_bf16(aH[m], bH[n], acc[m][n], 0, 0, 0);
                acc[m][n] = __builtin_amdgcn_mfma_f32_16x16x32_bf16(aH[m], bL[n], acc[m][n], 0, 0, 0);
                acc[m][n] = __builtin_amdgcn_mfma_f32_16x16x32_bf16(aL[m], bH[n], acc[m][n], 0, 0, 0);
            }
    };

    loadG(0, rA0, rB0);
    for (int kt = 0; kt < EH2; kt += 2 * BK) {
        writeL(rA0, rB0);
        __syncthreads();
        loadG(kt + BK, rA1, rB1);   // kt+32 <= 992 always valid
        compute();
        __syncthreads();
        writeL(rA1, rB1);
        __syncthreads();
        if (kt + 2 * BK < EH2) loadG(kt + 2 * BK, rA0, rB0);
        compute();
        __syncthreads();
    }

    // epilogue: partial scores = sum_d tanh(e_proj + h_proj)*v
    float hp[4], vv[4];
#pragma unroll
    for (int n = 0; n < 4; ++n) {
        int c = d0 + wd + n * 16 + lr;
        hp[n] = hproj[b * DH + c];
        vv[n] = v[c];
    }
    float* srowBase = scores + b * SS + s0 + ws;
#pragma unroll
    for (int m = 0; m < 4; ++m)
#pragma unroll
        for (int r = 0; r < 4; ++r) {
            float p = 0.f;
#pragma unroll
            for (int n = 0; n < 4; ++n)
                p += tanhf(acc[m][n][r] + hp[n]) * vv[n];
            p += __shfl_xor(p, 1, 64);
            p += __shfl_xor(p, 2, 64);
            p += __shfl_xor(p, 4, 64);
            p += __shfl_xor(p, 8, 64);
            if (lr == 0)
                atomicAdd(&srowBase[m * 16 + lg * 4 + r], p);
        }
}

// ---------------- Kernel C: masked softmax over S per batch row
__global__ void softmax_kernel(const float* __restrict__ scores,
                               const int* __restrict__ mask,
                               float* __restrict__ out) {
    __shared__ float red[8];
    int b = blockIdx.x;
    int tid = threadIdx.x;
    int lane = tid & 63;
    int wid = tid >> 6;

    float x[4];
    float mx = -INFINITY;
#pragma unroll
    for (int u = 0; u < 4; ++u) {
        int s = tid + 256 * u;
        float sc = scores[b * SS + s];
        if (mask[b * SS + s] == 0) sc = NEGV;
        x[u] = sc;
        mx = fmaxf(mx, sc);
    }
#pragma unroll
    for (int off = 32; off > 0; off >>= 1)
        mx = fmaxf(mx, __shfl_xor(mx, off, 64));
    if (lane == 0) red[wid] = mx;
    __syncthreads();
    mx = fmaxf(fmaxf(red[0], red[1]), fmaxf(red[2], red[3]));

    float sum = 0.f;
#pragma unroll
    for (int u = 0; u < 4; ++u) {
        x[u] = expf(x[u] - mx);
        sum += x[u];
    }
#pragma unroll
    for (int off = 32; off > 0; off >>= 1)
        sum += __shfl_xor(sum, off, 64);
    __syncthreads();
    if (lane == 0) red[4 + wid] = sum;
    __syncthreads();
    sum = red[4] + red[5] + red[6] + red[7];
    float inv = 1.0f / sum;
#pragma unroll
    for (int u = 0; u < 4; ++u)
        out[b * SS + tid + 256 * u] = x[u] * inv;
}

extern "C" void kernel_launch(void* const* d_in, const int* in_sizes, int n_in,
                              void* d_out, int out_size, void* d_ws, size_t ws_size,
                              hipStream_t stream) {
    const float* hidden = (const float*)d_in[0];
    const float* enc    = (const float*)d_in[1];
    const int*   mask   = (const int*)d_in[2];
    const float* W      = (const float*)d_in[3];
    const float* bias   = (const float*)d_in[4];
    const float* v      = (const float*)d_in[5];
    float* out = (float*)d_out;

    float* hproj  = (float*)d_ws;                       // 64 KB
    float* scores = (float*)((char*)d_ws + 64 * 1024);  // 128 KB

    hipMemsetAsync(scores, 0, BB * SS * sizeof(float), stream);

    hproj_kernel<<<BB * DH / 4, 256, 0, stream>>>(hidden, W, bias, hproj);
    energy_mfma_kernel<<<256 * 4, 256, 0, stream>>>(enc, W, hproj, v, scores);
    softmax_kernel<<<BB, 256, 0, stream>>>(scores, mask, out);
}

// Round 3
// 147.405 us; speedup vs baseline: 2.9992x; 1.0183x over previous
//
#include <hip/hip_runtime.h>
#include <hip/hip_bf16.h>
#include <math.h>

#define BB 32
#define SS 1024
#define DH 512      // DEC_HID
#define EH2 1024    // 2*ENC_HID
#define WROW 1536   // in_dim
#define NEGV -1.0e10f

#define BM 128
#define BN 256
#define BK 32
#define LSTR 40     // padded LDS row stride (bf16 elems) = 80 B

typedef __attribute__((ext_vector_type(8))) short s16x8;
typedef __attribute__((ext_vector_type(4))) float f32x4;

// ---------------- Kernel A: h_proj[b,d] = hidden[b,:] . W[d,:512] + bias[d]
__global__ void hproj_kernel(const float* __restrict__ hidden,
                             const float* __restrict__ W,
                             const float* __restrict__ bias,
                             float* __restrict__ hproj) {
    int wave = (int)((blockIdx.x * blockDim.x + threadIdx.x) >> 6);
    int lane = threadIdx.x & 63;
    if (wave >= BB * DH) return;
    int b = wave >> 9;
    int d = wave & 511;
    const float* hrow = hidden + b * DH;
    const float* wrow = W + (size_t)d * WROW;
    float sum = 0.f;
#pragma unroll
    for (int u = 0; u < 8; ++u) {
        int k = lane + 64 * u;
        sum = fmaf(hrow[k], wrow[k], sum);
    }
#pragma unroll
    for (int off = 32; off > 0; off >>= 1)
        sum += __shfl_xor(sum, off, 64);
    if (lane == 0) hproj[wave] = sum + bias[d];
}

// ---------------- Kernel B0: pre-split We into bf16 hi/lo planes
// We[c][k] = W[c*1536 + 512 + k], c in [0,512), k in [0,1024)
__global__ void bsplit_kernel(const float* __restrict__ W,
                              unsigned short* __restrict__ bh,
                              unsigned short* __restrict__ bl) {
    int idx = blockIdx.x * 256 + threadIdx.x;   // one float4 each; 131072 total
    int c = idx >> 8;
    int k4 = (idx & 255) * 4;
    float4 val = *(const float4*)(W + (size_t)c * WROW + DH + k4);
    float xs[4] = {val.x, val.y, val.z, val.w};
    unsigned long long whi = 0, wlo = 0;
#pragma unroll
    for (int j = 0; j < 4; ++j) {
        unsigned int u = __builtin_bit_cast(unsigned int, xs[j]);
        unsigned int hb = u & 0xFFFF0000u;
        float rem = xs[j] - __builtin_bit_cast(float, hb);
        __hip_bfloat16 lo16 = __float2bfloat16(rem);
        whi |= ((unsigned long long)(u >> 16)) << (16 * j);
        wlo |= ((unsigned long long)__builtin_bit_cast(unsigned short, lo16)) << (16 * j);
    }
    *(unsigned long long*)(bh + (size_t)c * EH2 + k4) = whi;
    *(unsigned long long*)(bl + (size_t)c * EH2 + k4) = wlo;
}

// ---------------- Kernel B: bf16-split MFMA GEMM + tanh·v epilogue
// grid: 256 m-blocks (b,s) x 2 n-blocks (d) = 512 blocks, 512 threads (8 waves)
__global__ __launch_bounds__(512, 1)
void energy_mfma_kernel(const float* __restrict__ enc,
                        const unsigned short* __restrict__ bspH,
                        const unsigned short* __restrict__ bspL,
                        const float* __restrict__ hproj,
                        const float* __restrict__ v,
                        float* __restrict__ scores) {
    __shared__ unsigned short sA[2][BM * LSTR];  // [0]=hi [1]=lo
    __shared__ unsigned short sB[2][BN * LSTR];

    const int tid = threadIdx.x;
    const int lane = tid & 63;
    const int wid = tid >> 6;
    const int lr = lane & 15;
    const int lg = lane >> 4;

    const int nblk = blockIdx.x & 1;
    const int mblk = blockIdx.x >> 1;
    const int b = mblk >> 3;
    const int s0 = (mblk & 7) * BM;
    const int d0 = nblk * BN;

    const int wm = (wid >> 2) * 64;  // wave row (s) offset in tile
    const int wn = (wid & 3) * 64;   // wave col (d) offset in tile

    const float* aBase = enc + (size_t)(b * SS + s0) * EH2;

    // A staging mapping: 128 rows x 32 k; 512 threads -> 8 f32 each
    const int arow = tid >> 2;           // 0..127
    const int ak = (tid & 3) * 8;        // 0,8,16,24
    // B staging mapping: 256 cols x 32 k; 512 threads -> 16 bf16 each (per plane)
    const int bcol = tid >> 1;           // 0..255
    const int bk = (tid & 1) * 16;       // 0,16

    const unsigned short* bhBase = bspH + (size_t)(d0 + bcol) * EH2 + bk;
    const unsigned short* blBase = bspL + (size_t)(d0 + bcol) * EH2 + bk;

    f32x4 acc[4][4];
#pragma unroll
    for (int m = 0; m < 4; ++m)
#pragma unroll
        for (int n = 0; n < 4; ++n) acc[m][n] = (f32x4){0.f, 0.f, 0.f, 0.f};

    float4 rA0[2], rA1[2];
    s16x8 rBh0[2], rBl0[2], rBh1[2], rBl1[2];

    auto loadG = [&](int kt, float4* a4, s16x8* bh, s16x8* bl) {
        a4[0] = *(const float4*)(aBase + (size_t)arow * EH2 + kt + ak);
        a4[1] = *(const float4*)(aBase + (size_t)arow * EH2 + kt + ak + 4);
        bh[0] = *(const s16x8*)(bhBase + kt);
        bh[1] = *(const s16x8*)(bhBase + kt + 8);
        bl[0] = *(const s16x8*)(blBase + kt);
        bl[1] = *(const s16x8*)(blBase + kt + 8);
    };

    auto splitWrite = [&](unsigned short* hiDst, unsigned short* loDst, const float4& val) {
        float xs[4] = {val.x, val.y, val.z, val.w};
        unsigned long long whi = 0, wlo = 0;
#pragma unroll
        for (int j = 0; j < 4; ++j) {
            unsigned int u = __builtin_bit_cast(unsigned int, xs[j]);
            unsigned int hb = u & 0xFFFF0000u;
            float rem = xs[j] - __builtin_bit_cast(float, hb);
            __hip_bfloat16 lo16 = __float2bfloat16(rem);
            whi |= ((unsigned long long)(u >> 16)) << (16 * j);
            wlo |= ((unsigned long long)__builtin_bit_cast(unsigned short, lo16)) << (16 * j);
        }
        *(unsigned long long*)hiDst = whi;
        *(unsigned long long*)loDst = wlo;
    };

    auto writeL = [&](const float4* a4, const s16x8* bh, const s16x8* bl) {
        int abase = arow * LSTR + ak;
        splitWrite(&sA[0][abase], &sA[1][abase], a4[0]);
        splitWrite(&sA[0][abase + 4], &sA[1][abase + 4], a4[1]);
        int bbase = bcol * LSTR + bk;
        *(s16x8*)&sB[0][bbase] = bh[0];
        *(s16x8*)&sB[0][bbase + 8] = bh[1];
        *(s16x8*)&sB[1][bbase] = bl[0];
        *(s16x8*)&sB[1][bbase + 8] = bl[1];
    };

    auto compute = [&]() {
        s16x8 aH[4], aL[4], bH[4], bL[4];
#pragma unroll
        for (int m = 0; m < 4; ++m) {
            int off = (wm + m * 16 + lr) * LSTR + lg * 8;
            aH[m] = *(const s16x8*)&sA[0][off];
            aL[m] = *(const s16x8*)&sA[1][off];
        }
#pragma unroll
        for (int n = 0; n < 4; ++n) {
            int off = (wn + n * 16 + lr) * LSTR + lg * 8;
            bH[n] = *(const s16x8*)&sB[0][off];
            bL[n] = *(const s16x8*)&sB[1][off];
        }
#pragma unroll
        for (int m = 0; m < 4; ++m)
#pragma unroll
            for (int n = 0; n < 4; ++n) {
                acc[m][n] = __builtin_amdgcn_mfma_f32_16x16x32_bf16(aH[m], bH[n], acc[m][n], 0, 0, 0);
                acc[m][n] = __builtin_amdgcn_mfma_f32_16x16x32_bf16(aH[m], bL[n], acc[m][n], 0, 0, 0);
                acc[m][n] = __builtin_amdgcn_mfma_f32_16x16x32_bf16(aL[m], bH[n], acc[m][n], 0, 0, 0);
            }
    };

    loadG(0, rA0, rBh0, rBl0);
    for (int kt = 0; kt < EH2; kt += 2 * BK) {
        writeL(rA0, rBh0, rBl0);
        __syncthreads();
        loadG(kt + BK, rA1, rBh1, rBl1);
        compute();
        __syncthreads();
        writeL(rA1, rBh1, rBl1);
        __syncthreads();
        if (kt + 2 * BK < EH2) loadG(kt + 2 * BK, rA0, rBh0, rBl0);
        compute();
        __syncthreads();
    }

    // epilogue: partial scores = sum_d tanh(e_proj + h_proj)*v
    float hp[4], vv[4];
#pragma unroll
    for (int n = 0; n < 4; ++n) {
        int c = d0 + wn + n * 16 + lr;
        hp[n] = hproj[b * DH + c];
        vv[n] = v[c];
    }
    float* srowBase = scores + b * SS + s0 + wm;
#pragma unroll
    for (int m = 0; m < 4; ++m)
#pragma unroll
        for (int r = 0; r < 4; ++r) {
            float p = 0.f;
#pragma unroll
            for (int n = 0; n < 4; ++n)
                p += tanhf(acc[m][n][r] + hp[n]) * vv[n];
            p += __shfl_xor(p, 1, 64);
            p += __shfl_xor(p, 2, 64);
            p += __shfl_xor(p, 4, 64);
            p += __shfl_xor(p, 8, 64);
            if (lr == 0)
                atomicAdd(&srowBase[m * 16 + lg * 4 + r], p);
        }
}

// ---------------- Kernel C: masked softmax over S per batch row
__global__ void softmax_kernel(const float* __restrict__ scores,
                               const int* __restrict__ mask,
                               float* __restrict__ out) {
    __shared__ float red[8];
    int b = blockIdx.x;
    int tid = threadIdx.x;
    int lane = tid & 63;
    int wid = tid >> 6;

    float x[4];
    float mx = -INFINITY;
#pragma unroll
    for (int u = 0; u < 4; ++u) {
        int s = tid + 256 * u;
        float sc = scores[b * SS + s];
        if (mask[b * SS + s] == 0) sc = NEGV;
        x[u] = sc;
        mx = fmaxf(mx, sc);
    }
#pragma unroll
    for (int off = 32; off > 0; off >>= 1)
        mx = fmaxf(mx, __shfl_xor(mx, off, 64));
    if (lane == 0) red[wid] = mx;
    __syncthreads();
    mx = fmaxf(fmaxf(red[0], red[1]), fmaxf(red[2], red[3]));

    float sum = 0.f;
#pragma unroll
    for (int u = 0; u < 4; ++u) {
        x[u] = expf(x[u] - mx);
        sum += x[u];
    }
#pragma unroll
    for (int off = 32; off > 0; off >>= 1)
        sum += __shfl_xor(sum, off, 64);
    __syncthreads();
    if (lane == 0) red[4 + wid] = sum;
    __syncthreads();
    sum = red[4] + red[5] + red[6] + red[7];
    float inv = 1.0f / sum;
#pragma unroll
    for (int u = 0; u < 4; ++u)
        out[b * SS + tid + 256 * u] = x[u] * inv;
}

extern "C" void kernel_launch(void* const* d_in, const int* in_sizes, int n_in,
                              void* d_out, int out_size, void* d_ws, size_t ws_size,
                              hipStream_t stream) {
    const float* hidden = (const float*)d_in[0];
    const float* enc    = (const float*)d_in[1];
    const int*   mask   = (const int*)d_in[2];
    const float* W      = (const float*)d_in[3];
    const float* bias   = (const float*)d_in[4];
    const float* v      = (const float*)d_in[5];
    float* out = (float*)d_out;

    float* hproj  = (float*)d_ws;                                   // 64 KB
    float* scores = (float*)((char*)d_ws + 64 * 1024);              // 128 KB
    unsigned short* bspH = (unsigned short*)((char*)d_ws + 192 * 1024);            // 1 MB
    unsigned short* bspL = (unsigned short*)((char*)d_ws + 192 * 1024 + DH * EH2 * 2);  // 1 MB

    hipMemsetAsync(scores, 0, BB * SS * sizeof(float), stream);

    bsplit_kernel<<<DH * EH2 / 4 / 256, 256, 0, stream>>>(W, bspH, bspL);
    hproj_kernel<<<BB * DH / 4, 256, 0, stream>>>(hidden, W, bias, hproj);
    energy_mfma_kernel<<<256 * 2, 512, 0, stream>>>(enc, bspH, bspL, hproj, v, scores);
    softmax_kernel<<<BB, 256, 0, stream>>>(scores, mask, out);
}

// Round 4
// 128.803 us; speedup vs baseline: 3.4324x; 1.1444x over previous
//
#include <hip/hip_runtime.h>
#include <hip/hip_bf16.h>
#include <math.h>

#define BB 32
#define SS 1024
#define DH 512      // DEC_HID
#define EH2 1024    // 2*ENC_HID
#define WROW 1536   // in_dim
#define NEGV -1.0e10f

typedef __attribute__((ext_vector_type(8))) short s16x8;
typedef __attribute__((ext_vector_type(4))) float f32x4;
typedef unsigned short u16;
typedef unsigned int u32;

// LDS row = 128 B: [hi k0..31 | lo k0..31], 8 slots of 16 B, XOR-swizzled.
// offset in ushort units.
__device__ __forceinline__ int swz(int row, int slot) {
    return row * 64 + ((slot ^ (row & 7)) << 3);
}

__device__ __forceinline__ void split8(const float4& v0, const float4& v1,
                                       s16x8& hi, s16x8& lo) {
    float xs[8] = {v0.x, v0.y, v0.z, v0.w, v1.x, v1.y, v1.z, v1.w};
    union { u16 u[8]; s16x8 v; } H, L;
#pragma unroll
    for (int j = 0; j < 8; ++j) {
        u32 u = __builtin_bit_cast(u32, xs[j]);
        u32 hb = u & 0xFFFF0000u;
        float rem = xs[j] - __builtin_bit_cast(float, hb);
        H.u[j] = (u16)(u >> 16);
        L.u[j] = __builtin_bit_cast(u16, __float2bfloat16(rem));
    }
    hi = H.v;
    lo = L.v;
}

// ---------------- Kernel A: h_proj[b,d] = hidden[b,:] . W[d,:512] + bias[d]
__global__ void hproj_kernel(const float* __restrict__ hidden,
                             const float* __restrict__ W,
                             const float* __restrict__ bias,
                             float* __restrict__ hproj) {
    int wave = (int)((blockIdx.x * blockDim.x + threadIdx.x) >> 6);
    int lane = threadIdx.x & 63;
    if (wave >= BB * DH) return;
    int b = wave >> 9;
    int d = wave & 511;
    const float* hrow = hidden + b * DH;
    const float* wrow = W + (size_t)d * WROW;
    float sum = 0.f;
#pragma unroll
    for (int u = 0; u < 8; ++u) {
        int k = lane + 64 * u;
        sum = fmaf(hrow[k], wrow[k], sum);
    }
#pragma unroll
    for (int off = 32; off > 0; off >>= 1)
        sum += __shfl_xor(sum, off, 64);
    if (lane == 0) hproj[wave] = sum + bias[d];
}

// ---------------- Kernel B0: pre-split We into swizzled per-(nblk,kt) tile images
// Tile (nb 0..3, kt 0..31): 128 cols x 32 k, hi/lo interleaved per row, swizzled.
// Image layout == desired LDS image, so global_load_lds (linear) reproduces it.
__global__ void bsplit_kernel(const float* __restrict__ W,
                              u16* __restrict__ img) {
    int idx = blockIdx.x * 256 + threadIdx.x;   // 512 cols * 128 k-octets = 65536
    int c = idx >> 7;         // 0..511 (We row = output col d)
    int ko = idx & 127;       // k-octet 0..127
    int k = ko * 8;
    const float* src = W + (size_t)c * WROW + DH + k;
    float4 v0 = *(const float4*)src;
    float4 v1 = *(const float4*)(src + 4);
    s16x8 hi, lo;
    split8(v0, v1, hi, lo);
    int nb = c >> 7;          // n-block
    int cp = c & 127;         // col within tile
    int kt = ko >> 2;         // K-step
    int sl = ko & 3;          // hi slot
    u16* tb = img + ((size_t)(nb * 32 + kt) << 13);   // 8192 ushorts per tile
    *(s16x8*)(tb + swz(cp, sl)) = hi;
    *(s16x8*)(tb + swz(cp, sl + 4)) = lo;
}

// ---------------- Kernel B: bf16-split MFMA GEMM + tanh·v epilogue
// grid: 1024 blocks (XCD-decoded: 256 m-blocks x 4 n-blocks), 256 threads (4 waves)
__global__ __launch_bounds__(256, 2)
void energy_mfma_kernel(const float* __restrict__ enc,
                       const u16* __restrict__ bimg,
                       const float* __restrict__ hproj,
                       const float* __restrict__ v,
                       float* __restrict__ scores) {
    __shared__ u16 sA[2][128 * 64];   // 32 KB
    __shared__ u16 sB[2][128 * 64];   // 32 KB

    const int tid = threadIdx.x;
    const int lane = tid & 63;
    const int wid = tid >> 6;
    const int lr = lane & 15;
    const int lg = lane >> 4;

    // XCD-aware decode: the 4 nblk-siblings of one mblk land on the same XCD
    const int bid = blockIdx.x;
    const int mblk = (bid & 7) * 32 + (bid >> 5);   // 0..255
    const int nblk = (bid >> 3) & 3;                // 0..3
    const int b = mblk >> 3;
    const int s0 = (mblk & 7) * 128;
    const int d0 = nblk * 128;

    const int wm = (wid >> 1) * 64;   // wave row (s) offset
    const int wn = (wid & 1) * 64;    // wave col (d) offset

    const float* aBase = enc + ((size_t)(b * SS + s0)) * EH2;
    const u16* tBase = bimg + ((size_t)nblk << 18);   // nblk*32 tiles*8192

    const int ar = tid >> 2;   // A staging row 0..63 (+64)
    const int sl = tid & 3;    // A staging k-octet

    f32x4 acc[4][4];
#pragma unroll
    for (int m = 0; m < 4; ++m)
#pragma unroll
        for (int n = 0; n < 4; ++n) acc[m][n] = (f32x4){0.f, 0.f, 0.f, 0.f};

    float4 rA[4];

    auto loadA = [&](int t) {
        const float* p = aBase + (size_t)ar * EH2 + t * 32 + sl * 8;
        rA[0] = *(const float4*)p;
        rA[1] = *(const float4*)(p + 4);
        const float* p2 = p + (size_t)64 * EH2;
        rA[2] = *(const float4*)p2;
        rA[3] = *(const float4*)(p2 + 4);
    };

    auto writeA = [&](int buf) {
#pragma unroll
        for (int p = 0; p < 2; ++p) {
            int row = ar + 64 * p;
            s16x8 hi, lo;
            split8(rA[2 * p], rA[2 * p + 1], hi, lo);
            *(s16x8*)&sA[buf][swz(row, sl)] = hi;
            *(s16x8*)&sA[buf][swz(row, sl + 4)] = lo;
        }
    };

    auto stageB = [&](int t, int buf) {
        const u16* tb = tBase + ((size_t)t << 13);
        int off = wid << 9;   // wave-uniform, ushort units (1 KB per wave chunk)
#pragma unroll
        for (int q = 0; q < 4; ++q) {
            int o = off + (q << 11);
            __builtin_amdgcn_global_load_lds(
                (const __attribute__((address_space(1))) u32*)(tb + o + lane * 8),
                (__attribute__((address_space(3))) u32*)&sB[buf][o],
                16, 0, 0);
        }
    };

    auto compute = [&](int buf) {
        s16x8 aH[4], aL[4], bH[4], bL[4];
#pragma unroll
        for (int m = 0; m < 4; ++m) {
            int row = wm + m * 16 + lr;
            aH[m] = *(const s16x8*)&sA[buf][swz(row, lg)];
            aL[m] = *(const s16x8*)&sA[buf][swz(row, lg + 4)];
        }
#pragma unroll
        for (int n = 0; n < 4; ++n) {
            int col = wn + n * 16 + lr;
            bH[n] = *(const s16x8*)&sB[buf][swz(col, lg)];
            bL[n] = *(const s16x8*)&sB[buf][swz(col, lg + 4)];
        }
        __builtin_amdgcn_s_setprio(1);
#pragma unroll
        for (int m = 0; m < 4; ++m)
#pragma unroll
            for (int n = 0; n < 4; ++n) {
                acc[m][n] = __builtin_amdgcn_mfma_f32_16x16x32_bf16(aH[m], bH[n], acc[m][n], 0, 0, 0);
                acc[m][n] = __builtin_amdgcn_mfma_f32_16x16x32_bf16(aH[m], bL[n], acc[m][n], 0, 0, 0);
                acc[m][n] = __builtin_amdgcn_mfma_f32_16x16x32_bf16(aL[m], bH[n], acc[m][n], 0, 0, 0);
            }
        __builtin_amdgcn_s_setprio(0);
    };

    // prologue: stage K-step 0 into buf 0
    stageB(0, 0);
    loadA(0);
    writeA(0);
    __syncthreads();

    for (int t = 0; t < 32; ++t) {
        int cur = t & 1;
        if (t < 31) {
            loadA(t + 1);            // issue early (T14)
            stageB(t + 1, cur ^ 1);  // gload_lds in flight across compute
        }
        compute(cur);
        if (t < 31) writeA(cur ^ 1); // vmcnt-waits A regs, writes next buffer
        __syncthreads();
    }

    // epilogue: partial scores = sum_d tanh(e_proj + h_proj)*v
    float hp[4], vv[4];
#pragma unroll
    for (int n = 0; n < 4; ++n) {
        int c = d0 + wn + n * 16 + lr;
        hp[n] = hproj[b * DH + c];
        vv[n] = v[c];
    }
    float* srowBase = scores + b * SS + s0 + wm;
#pragma unroll
    for (int m = 0; m < 4; ++m)
#pragma unroll
        for (int r = 0; r < 4; ++r) {
            float p = 0.f;
#pragma unroll
            for (int n = 0; n < 4; ++n)
                p += tanhf(acc[m][n][r] + hp[n]) * vv[n];
            p += __shfl_xor(p, 1, 64);
            p += __shfl_xor(p, 2, 64);
            p += __shfl_xor(p, 4, 64);
            p += __shfl_xor(p, 8, 64);
            if (lr == 0)
                atomicAdd(&srowBase[m * 16 + lg * 4 + r], p);
        }
}

// ---------------- Kernel C: masked softmax over S per batch row
__global__ void softmax_kernel(const float* __restrict__ scores,
                               const int* __restrict__ mask,
                               float* __restrict__ out) {
    __shared__ float red[8];
    int b = blockIdx.x;
    int tid = threadIdx.x;
    int lane = tid & 63;
    int wid = tid >> 6;

    float x[4];
    float mx = -INFINITY;
#pragma unroll
    for (int u = 0; u < 4; ++u) {
        int s = tid + 256 * u;
        float sc = scores[b * SS + s];
        if (mask[b * SS + s] == 0) sc = NEGV;
        x[u] = sc;
        mx = fmaxf(mx, sc);
    }
#pragma unroll
    for (int off = 32; off > 0; off >>= 1)
        mx = fmaxf(mx, __shfl_xor(mx, off, 64));
    if (lane == 0) red[wid] = mx;
    __syncthreads();
    mx = fmaxf(fmaxf(red[0], red[1]), fmaxf(red[2], red[3]));

    float sum = 0.f;
#pragma unroll
    for (int u = 0; u < 4; ++u) {
        x[u] = expf(x[u] - mx);
        sum += x[u];
    }
#pragma unroll
    for (int off = 32; off > 0; off >>= 1)
        sum += __shfl_xor(sum, off, 64);
    __syncthreads();
    if (lane == 0) red[4 + wid] = sum;
    __syncthreads();
    sum = red[4] + red[5] + red[6] + red[7];
    float inv = 1.0f / sum;
#pragma unroll
    for (int u = 0; u < 4; ++u)
        out[b * SS + tid + 256 * u] = x[u] * inv;
}

extern "C" void kernel_launch(void* const* d_in, const int* in_sizes, int n_in,
                              void* d_out, int out_size, void* d_ws, size_t ws_size,
                              hipStream_t stream) {
    const float* hidden = (const float*)d_in[0];
    const float* enc    = (const float*)d_in[1];
    const int*   mask   = (const int*)d_in[2];
    const float* W      = (const float*)d_in[3];
    const float* bias   = (const float*)d_in[4];
    const float* v      = (const float*)d_in[5];
    float* out = (float*)d_out;

    float* hproj = (float*)d_ws;                          // 64 KB
    float* scores = (float*)((char*)d_ws + 64 * 1024);    // 128 KB
    u16* bimg = (u16*)((char*)d_ws + 192 * 1024);         // 2 MB swizzled tiles

    hipMemsetAsync(scores, 0, BB * SS * sizeof(float), stream);

    bsplit_kernel<<<256, 256, 0, stream>>>(W, bimg);
    hproj_kernel<<<BB * DH / 4, 256, 0, stream>>>(hidden, W, bias, hproj);
    energy_mfma_kernel<<<1024, 256, 0, stream>>>(enc, bimg, hproj, v, scores);
    softmax_kernel<<<BB, 256, 0, stream>>>(scores, mask, out);
}

// Round 5
// 119.975 us; speedup vs baseline: 3.6849x; 1.0736x over previous
//
#include <hip/hip_runtime.h>
#include <hip/hip_bf16.h>
#include <math.h>

#define BB 32
#define SS 1024
#define DH 512      // DEC_HID
#define EH2 1024    // 2*ENC_HID
#define WROW 1536   // in_dim
#define NEGV -1.0e10f

typedef __attribute__((ext_vector_type(8))) short s16x8;
typedef __attribute__((ext_vector_type(4))) float f32x4;
typedef unsigned short u16;
typedef unsigned int u32;

// LDS row = 128 B: [hi k0..31 | lo k0..31], 8 slots of 16 B, XOR-swizzled.
__device__ __forceinline__ int swz(int row, int slot) {
    return row * 64 + ((slot ^ (row & 7)) << 3);
}

__device__ __forceinline__ void split8(const float4& v0, const float4& v1,
                                       s16x8& hi, s16x8& lo) {
    float xs[8] = {v0.x, v0.y, v0.z, v0.w, v1.x, v1.y, v1.z, v1.w};
    union { u16 u[8]; s16x8 v; } H, L;
#pragma unroll
    for (int j = 0; j < 8; ++j) {
        u32 u = __builtin_bit_cast(u32, xs[j]);
        u32 hb = u & 0xFFFF0000u;
        float rem = xs[j] - __builtin_bit_cast(float, hb);
        H.u[j] = (u16)(u >> 16);
        L.u[j] = __builtin_bit_cast(u16, __float2bfloat16(rem));
    }
    hi = H.v;
    lo = L.v;
}

__device__ __forceinline__ float fast_tanh(float x) {
    float a = fabsf(x);
    float e = __expf(2.0f * a);
    float r = 1.0f - 2.0f / (e + 1.0f);   // e->inf gives r=1, no NaN
    return copysignf(r, x);
}

// ---------------- Kernel A: h_proj[b,d] = hidden[b,:] . W[d,:512] + bias[d]
__global__ void hproj_kernel(const float* __restrict__ hidden,
                             const float* __restrict__ W,
                             const float* __restrict__ bias,
                             float* __restrict__ hproj) {
    int wave = (int)((blockIdx.x * blockDim.x + threadIdx.x) >> 6);
    int lane = threadIdx.x & 63;
    if (wave >= BB * DH) return;
    int b = wave >> 9;
    int d = wave & 511;
    const float* hrow = hidden + b * DH;
    const float* wrow = W + (size_t)d * WROW;
    float sum = 0.f;
#pragma unroll
    for (int u = 0; u < 8; ++u) {
        int k = lane + 64 * u;
        sum = fmaf(hrow[k], wrow[k], sum);
    }
#pragma unroll
    for (int off = 32; off > 0; off >>= 1)
        sum += __shfl_xor(sum, off, 64);
    if (lane == 0) hproj[wave] = sum + bias[d];
}

// ---------------- Kernel B0: pre-split We into swizzled per-(nblk,kt) tile images
// Tile (nb 0..1, kt 0..31): 256 cols x 32 k, hi/lo per 128B row, swizzled.
// Image layout == desired LDS image so global_load_lds (linear) reproduces it.
__global__ void bsplit_kernel(const float* __restrict__ W,
                              u16* __restrict__ img) {
    int idx = blockIdx.x * 256 + threadIdx.x;   // 512 cols * 128 k-octets
    int c = idx >> 7;         // 0..511 (We row = output col d)
    int ko = idx & 127;       // k-octet 0..127
    int k = ko * 8;
    const float* src = W + (size_t)c * WROW + DH + k;
    float4 v0 = *(const float4*)src;
    float4 v1 = *(const float4*)(src + 4);
    s16x8 hi, lo;
    split8(v0, v1, hi, lo);
    int nb = c >> 8;          // n-block (256 cols each)
    int cp = c & 255;         // col within tile
    int kt = ko >> 2;         // K-step
    int sl = ko & 3;          // hi slot
    u16* tb = img + ((size_t)(nb * 32 + kt) << 14);   // 16384 ushorts per tile
    *(s16x8*)(tb + swz(cp, sl)) = hi;
    *(s16x8*)(tb + swz(cp, sl + 4)) = lo;
}

// ---------------- Kernel B: 8-wave 256x256 tile, counted-vmcnt pipeline
// grid: 256 blocks (128 m x 2 n, XCD-chunked), 512 threads
__global__ __launch_bounds__(512, 2)
void energy_mfma_kernel(const float* __restrict__ enc,
                        const u16* __restrict__ bimg,
                        const float* __restrict__ hproj,
                        const float* __restrict__ v,
                        float* __restrict__ scores) {
    __shared__ u16 sA[2][256 * 64];   // 32 KB each
    __shared__ u16 sB[2][256 * 64];

    const int tid = threadIdx.x;
    const int lane = tid & 63;
    const int wid = tid >> 6;
    const int lr = lane & 15;
    const int lg = lane >> 4;

    // XCD-chunked decode: 8 XCDs x 32 contiguous flat ids
    const int flat = (blockIdx.x & 7) * 32 + (blockIdx.x >> 3);
    const int nblk = flat & 1;
    const int mblk = flat >> 1;       // 0..127
    const int b = mblk >> 2;
    const int srow = (mblk & 3) * 256;
    const int d0 = nblk * 256;

    const int wm = (wid >> 2) * 128;  // wave row offset (2 M-waves)
    const int wn = (wid & 3) * 64;    // wave col offset (4 N-waves)

    const float* aBase = enc + ((size_t)(b * SS + srow)) * EH2;
    const u16* tBase = bimg + (((size_t)nblk * 32) << 14);

    const int arow = tid >> 1;        // 0..255
    const int ahalf = tid & 1;        // k 0..15 / 16..31

    f32x4 acc[8][4];
#pragma unroll
    for (int m = 0; m < 8; ++m)
#pragma unroll
        for (int n = 0; n < 4; ++n) acc[m][n] = (f32x4){0.f, 0.f, 0.f, 0.f};

    float4 rA[4];
    auto loadA = [&](int t) {
        const float* p = aBase + (size_t)arow * EH2 + t * 32 + ahalf * 16;
        rA[0] = ((const float4*)p)[0];
        rA[1] = ((const float4*)p)[1];
        rA[2] = ((const float4*)p)[2];
        rA[3] = ((const float4*)p)[3];
    };
    auto writeA = [&](int buf) {
        s16x8 h0, l0, h1, l1;
        split8(rA[0], rA[1], h0, l0);
        split8(rA[2], rA[3], h1, l1);
        u16* base = &sA[buf][0];
        *(s16x8*)&base[swz(arow, ahalf * 2)]     = h0;
        *(s16x8*)&base[swz(arow, ahalf * 2 + 1)] = h1;
        *(s16x8*)&base[swz(arow, 4 + ahalf * 2)]     = l0;
        *(s16x8*)&base[swz(arow, 4 + ahalf * 2 + 1)] = l1;
    };
    auto stageB = [&](int t, int buf) {
        const u16* tb = tBase + ((size_t)t << 14);
#pragma unroll
        for (int q = 0; q < 4; ++q) {
            int o = (wid * 4 + q) * 512;   // ushort units, 1 KB per inst
            __builtin_amdgcn_global_load_lds(
                (const __attribute__((address_space(1))) u32*)(tb + o + lane * 8),
                (__attribute__((address_space(3))) u32*)&sB[buf][o],
                16, 0, 0);
        }
    };

    s16x8 bH[4], bL[4];
    auto readB = [&](int buf) {
#pragma unroll
        for (int n = 0; n < 4; ++n) {
            int col = wn + n * 16 + lr;
            bH[n] = *(const s16x8*)&sB[buf][swz(col, lg)];
            bL[n] = *(const s16x8*)&sB[buf][swz(col, lg + 4)];
        }
    };
    auto phase = [&](int buf, int p) {
        s16x8 aH[2], aL[2];
#pragma unroll
        for (int i = 0; i < 2; ++i) {
            int row = wm + (p * 2 + i) * 16 + lr;
            aH[i] = *(const s16x8*)&sA[buf][swz(row, lg)];
            aL[i] = *(const s16x8*)&sA[buf][swz(row, lg + 4)];
        }
        __builtin_amdgcn_s_barrier();
        __builtin_amdgcn_s_setprio(1);
#pragma unroll
        for (int i = 0; i < 2; ++i) {
            int m = p * 2 + i;
#pragma unroll
            for (int n = 0; n < 4; ++n) {
                acc[m][n] = __builtin_amdgcn_mfma_f32_16x16x32_bf16(aH[i], bH[n], acc[m][n], 0, 0, 0);
                acc[m][n] = __builtin_amdgcn_mfma_f32_16x16x32_bf16(aH[i], bL[n], acc[m][n], 0, 0, 0);
                acc[m][n] = __builtin_amdgcn_mfma_f32_16x16x32_bf16(aL[i], bH[n], acc[m][n], 0, 0, 0);
            }
        }
        __builtin_amdgcn_s_setprio(0);
        __builtin_amdgcn_s_barrier();
    };

    // ---- prologue: fill buffer 0
    stageB(0, 0);
    loadA(0);
    writeA(0);   // compiler auto-waits rA (drains B(0) too; prologue only)

#pragma unroll 1
    for (int t = 0; t < 31; ++t) {
        const int cur = t & 1;
        loadA(t + 1);                                   // A(t+1): 4 vmem, newest
        asm volatile("s_waitcnt vmcnt(4) lgkmcnt(0)" ::: "memory"); // waits B(t), keeps A(t+1) in flight
        __builtin_amdgcn_s_barrier();                   // whole tile [cur] now valid
        __builtin_amdgcn_sched_barrier(0);
        readB(cur);
        phase(cur, 0);
        stageB(t + 1, cur ^ 1);                         // B(t+1): 4 gload_lds, newest
        phase(cur, 1);
        phase(cur, 2);
        writeA(cur ^ 1);                                // auto vmcnt(4): waits A(t+1), B(t+1) flies
        phase(cur, 3);
    }
    // ---- peeled last step (t = 31, buffer 1), no staging
    asm volatile("s_waitcnt vmcnt(0) lgkmcnt(0)" ::: "memory");
    __builtin_amdgcn_s_barrier();
    __builtin_amdgcn_sched_barrier(0);
    readB(1);
    phase(1, 0);
    phase(1, 1);
    phase(1, 2);
    phase(1, 3);

    // ---- epilogue: partial scores = sum_d tanh(e_proj + h_proj)*v
    float hp[4], vv[4];
#pragma unroll
    for (int n = 0; n < 4; ++n) {
        int c = d0 + wn + n * 16 + lr;
        hp[n] = hproj[b * DH + c];
        vv[n] = v[c];
    }
    float* srowBase = scores + b * SS + srow + wm;
#pragma unroll
    for (int m = 0; m < 8; ++m)
#pragma unroll
        for (int r = 0; r < 4; ++r) {
            float p = 0.f;
#pragma unroll
            for (int n = 0; n < 4; ++n)
                p += fast_tanh(acc[m][n][r] + hp[n]) * vv[n];
            p += __shfl_xor(p, 1, 64);
            p += __shfl_xor(p, 2, 64);
            p += __shfl_xor(p, 4, 64);
            p += __shfl_xor(p, 8, 64);
            if (lr == 0)
                atomicAdd(&srowBase[m * 16 + lg * 4 + r], p);
        }
}

// ---------------- Kernel C: masked softmax over S per batch row
__global__ void softmax_kernel(const float* __restrict__ scores,
                               const int* __restrict__ mask,
                               float* __restrict__ out) {
    __shared__ float red[8];
    int b = blockIdx.x;
    int tid = threadIdx.x;
    int lane = tid & 63;
    int wid = tid >> 6;

    float x[4];
    float mx = -INFINITY;
#pragma unroll
    for (int u = 0; u < 4; ++u) {
        int s = tid + 256 * u;
        float sc = scores[b * SS + s];
        if (mask[b * SS + s] == 0) sc = NEGV;
        x[u] = sc;
        mx = fmaxf(mx, sc);
    }
#pragma unroll
    for (int off = 32; off > 0; off >>= 1)
        mx = fmaxf(mx, __shfl_xor(mx, off, 64));
    if (lane == 0) red[wid] = mx;
    __syncthreads();
    mx = fmaxf(fmaxf(red[0], red[1]), fmaxf(red[2], red[3]));

    float sum = 0.f;
#pragma unroll
    for (int u = 0; u < 4; ++u) {
        x[u] = expf(x[u] - mx);
        sum += x[u];
    }
#pragma unroll
    for (int off = 32; off > 0; off >>= 1)
        sum += __shfl_xor(sum, off, 64);
    __syncthreads();
    if (lane == 0) red[4 + wid] = sum;
    __syncthreads();
    sum = red[4] + red[5] + red[6] + red[7];
    float inv = 1.0f / sum;
#pragma unroll
    for (int u = 0; u < 4; ++u)
        out[b * SS + tid + 256 * u] = x[u] * inv;
}

extern "C" void kernel_launch(void* const* d_in, const int* in_sizes, int n_in,
                              void* d_out, int out_size, void* d_ws, size_t ws_size,
                              hipStream_t stream) {
    const float* hidden = (const float*)d_in[0];
    const float* enc    = (const float*)d_in[1];
    const int*   mask   = (const int*)d_in[2];
    const float* W      = (const float*)d_in[3];
    const float* bias   = (const float*)d_in[4];
    const float* v      = (const float*)d_in[5];
    float* out = (float*)d_out;

    float* hproj = (float*)d_ws;                          // 64 KB
    float* scores = (float*)((char*)d_ws + 64 * 1024);    // 128 KB
    u16* bimg = (u16*)((char*)d_ws + 192 * 1024);         // 2 MB swizzled tiles

    hipMemsetAsync(scores, 0, BB * SS * sizeof(float), stream);

    bsplit_kernel<<<256, 256, 0, stream>>>(W, bimg);
    hproj_kernel<<<BB * DH / 4, 256, 0, stream>>>(hidden, W, bias, hproj);
    energy_mfma_kernel<<<256, 512, 0, stream>>>(enc, bimg, hproj, v, scores);
    softmax_kernel<<<BB, 256, 0, stream>>>(scores, mask, out);
}